// Round 14
// baseline (174.494 us; speedup 1.0000x reference)
//
#include <hip/hip_runtime.h>
#include <hip/hip_bf16.h>
#include <stdint.h>

#define B_ 8
#define N_ 1024
#define E_ 768
#define H_ 12
#define HD_ 64
#define M_ (B_ * N_)   // 8192 rows

typedef __attribute__((ext_vector_type(8))) short bf8_t;    // 8 x bf16
typedef __attribute__((ext_vector_type(4))) float f4_t;     // 4 x f32
typedef __attribute__((ext_vector_type(16))) float f16_t;   // 16 x f32 (32x32 acc)

__device__ __forceinline__ unsigned short f2bf(float f) {
  unsigned u = __builtin_bit_cast(unsigned, f);
  unsigned r = (u + 0x7fffu + ((u >> 16) & 1u)) >> 16;  // RNE
  return (unsigned short)r;
}

__device__ __forceinline__ unsigned cvt_pk_bf16(float lo, float hi) {
  unsigned r;
  asm("v_cvt_pk_bf16_f32 %0, %1, %2" : "=v"(r) : "v"(lo), "v"(hi));
  return r;
}

__device__ __forceinline__ float exp2_hw(float x) {
  float r;
  asm("v_exp_f32 %0, %1" : "=v"(r) : "v"(x));
  return r;
}

__device__ __forceinline__ void load_lds16(const void* g, void* l) {
  __builtin_amdgcn_global_load_lds(
      (__attribute__((address_space(1))) void*)(g),
      (__attribute__((address_space(3))) void*)(l), 16, 0, 0);
}

#define WAITV(N)                                        \
  asm volatile("s_waitcnt vmcnt(" #N ")" ::: "memory"); \
  __builtin_amdgcn_sched_barrier(0);                    \
  __builtin_amdgcn_s_barrier();                         \
  __builtin_amdgcn_sched_barrier(0);

#define BAR2()                          \
  __builtin_amdgcn_sched_barrier(0);    \
  __builtin_amdgcn_s_barrier();         \
  __builtin_amdgcn_sched_barrier(0);

// XOR swizzle on the 8-elem (16B) chunk within a 64-elem (128B) row.
__device__ __forceinline__ int swz(int row) {
  return ((row ^ (row >> 3)) & 7) << 3;
}

#define F3(a, b, c) fmaxf(fmaxf((a), (b)), (c))   // fuses to v_max3_f32

// ---------------- weight fp32 -> bf16 cast (vectorized) ----------------
__global__ void k_cast_bf16(const float* __restrict__ in,
                            unsigned short* __restrict__ out, int n4) {
  int i = blockIdx.x * blockDim.x + threadIdx.x;
  if (i < n4) {
    float4 v = ((const float4*)in)[i];
    ushort4 o;
    o.x = f2bf(v.x); o.y = f2bf(v.y); o.z = f2bf(v.z); o.w = f2bf(v.w);
    ((ushort4*)out)[i] = o;
  }
}

// ---------------- LayerNorm -> bf16 ----------------
__global__ __launch_bounds__(192) void k_ln(const float* __restrict__ x,
                                            const float* __restrict__ g,
                                            const float* __restrict__ bta,
                                            unsigned short* __restrict__ xn) {
  int row = blockIdx.x;  // 8192
  int t = threadIdx.x;   // 0..191
  float4 v = ((const float4*)(x + (size_t)row * E_))[t];
  float s = v.x + v.y + v.z + v.w;
  float s2 = v.x * v.x + v.y * v.y + v.z * v.z + v.w * v.w;
  for (int off = 32; off; off >>= 1) {
    s += __shfl_xor(s, off, 64);
    s2 += __shfl_xor(s2, off, 64);
  }
  __shared__ float red[6];
  int lane = t & 63, wv = t >> 6;
  if (lane == 0) { red[wv] = s; red[3 + wv] = s2; }
  __syncthreads();
  s = red[0] + red[1] + red[2];
  s2 = red[3] + red[4] + red[5];
  float mu = s * (1.0f / E_);
  float var = s2 * (1.0f / E_) - mu * mu;
  float rstd = rsqrtf(var + 1e-5f);
  float4 gg = ((const float4*)g)[t];
  float4 bb = ((const float4*)bta)[t];
  ushort4 o;
  o.x = f2bf((v.x - mu) * rstd * gg.x + bb.x);
  o.y = f2bf((v.y - mu) * rstd * gg.y + bb.y);
  o.z = f2bf((v.z - mu) * rstd * gg.z + bb.z);
  o.w = f2bf((v.w - mu) * rstd * gg.w + bb.w);
  ((ushort4*)(xn + (size_t)row * E_))[t] = o;
}

// ---------------- GEMM  C = A @ W^T + bias ------------------------------------
// Round-8 schedule, but the B (weight) operand is loaded DIRECTLY from global
// (L2-resident, 16B/lane with full 64B-line utilization) — no B staging, no B
// LDS reads. LDS = A-only 32 KB dbuf -> 3-4 blocks/CU. Halves the LDS-pipe
// traffic that the cycle model shows is the binding constraint.
// EPI 0: scatter Q(*0.125*log2e)/K/V^T bf16;  EPI 1: dense fp32.
template <int EPI>
__global__ __launch_bounds__(256, 3) void k_gemm_bt(
    const unsigned short* __restrict__ A,   // [M][K] bf16
    const unsigned short* __restrict__ W,   // [Nf][K] bf16
    const float* __restrict__ bias,         // [Nf]
    unsigned short* __restrict__ oQ, unsigned short* __restrict__ oK,
    unsigned short* __restrict__ oVt, float* __restrict__ oF,
    int K, int Nf) {
  __shared__ unsigned short Al[2][128 * 64];   // 16 KB each, 32 KB total
  const int nbx = Nf >> 7;                  // 18 or 6
  const int nwg = nbx << 6;                 // %8 == 0
  const int orig = blockIdx.y * nbx + blockIdx.x;
  const int id = (orig & 7) * (nwg >> 3) + (orig >> 3);
  const int n0 = (id % nbx) * 128, m0 = (id / nbx) * 128;
  const int tid = threadIdx.x;
  const int lane = tid & 63, wv = tid >> 6;
  const int wr = wv >> 1, wc = wv & 1;      // 2x2 waves of 64x64
  const int g = lane >> 4, l15 = lane & 15;
  f4_t acc[4][4] = {};

  // per-lane B row pointers (fixed across K-loop)
  const unsigned short* Wr[4];
#pragma unroll
  for (int ni = 0; ni < 4; ++ni)
    Wr[ni] = W + (size_t)(n0 + wc * 64 + ni * 16 + l15) * K + g * 8;

  auto stageA = [&](int k0, int buf) {      // 4 loads / thread
#pragma unroll
    for (int i = 0; i < 4; ++i) {
      int e = (i * 256 + tid) * 8;          // 128x64 tile
      int r = e >> 6;
      int c = (e & 63) ^ swz(r);            // inverse-swizzled source column
      load_lds16(A + (size_t)(m0 + r) * K + (k0 + c), &Al[buf][e]);
    }
  };

  stageA(0, 0);
  __syncthreads();
  int cur = 0;

  for (int k0 = 0; k0 < K; k0 += 64) {
    if (k0 + 64 < K) stageA(k0 + 64, cur ^ 1);  // prefetch next A-tile
    // B fragments straight from global (L2): 8 x 16B per lane, issued early
    bf8_t bfr[2][4];
#pragma unroll
    for (int kk = 0; kk < 2; ++kk)
#pragma unroll
      for (int ni = 0; ni < 4; ++ni)
        bfr[kk][ni] = *(const bf8_t*)&Wr[ni][k0 + kk * 32];

    const unsigned short* Ac = Al[cur];
#pragma unroll
    for (int kk = 0; kk < 2; ++kk) {
      bf8_t af[4];
#pragma unroll
      for (int mi = 0; mi < 4; ++mi) {
        int ar = wr * 64 + mi * 16 + l15;
        af[mi] = *(const bf8_t*)&Ac[(ar * 64 + kk * 32 + g * 8) ^ swz(ar)];
      }
#pragma unroll
      for (int mi = 0; mi < 4; ++mi)
#pragma unroll
        for (int ni = 0; ni < 4; ++ni)
          acc[mi][ni] = __builtin_amdgcn_mfma_f32_16x16x32_bf16(
              af[mi], bfr[kk][ni], acc[mi][ni], 0, 0, 0);
    }
    __syncthreads();   // A-prefetch landed; all waves done reading Al[cur]
    cur ^= 1;
  }

#pragma unroll
  for (int mi = 0; mi < 4; ++mi) {
#pragma unroll
    for (int ni = 0; ni < 4; ++ni) {
      int f = n0 + wc * 64 + ni * 16 + l15;
      float bs = bias[f];
#pragma unroll
      for (int i = 0; i < 4; ++i) {
        int m = m0 + wr * 64 + mi * 16 + g * 4 + i;
        float val = acc[mi][ni][i] + bs;
        if (EPI == 0) {
          int bb = m >> 10, n = m & 1023;
          int which = f / E_;
          int e2 = f - which * E_;
          int h = e2 >> 6, d = e2 & 63;
          size_t qk = (((size_t)bb * H_ + h) * N_ + n) * HD_ + d;
          if (which == 0) oQ[qk] = f2bf(val * 0.1803368801f);  // 0.125*log2(e)
          else if (which == 1) oK[qk] = f2bf(val);
          else oVt[(((size_t)bb * H_ + h) * HD_ + d) * N_ + n] = f2bf(val);
        } else {
          oF[(size_t)m * E_ + f] = val;
        }
      }
    }
  }
}

// ---------------- flash attention: 32x32 MFMA, in-register P ------------------
// 4 waves x 32 q-rows (128 q/block, grid 768 = 3 blocks/CU, full residency).
__global__ __launch_bounds__(256, 3) void k_attn(
    const unsigned short* __restrict__ Q,   // [bh][n][64], pre-scaled
    const unsigned short* __restrict__ Kb,  // [bh][n][64]
    const unsigned short* __restrict__ Vt,  // [bh][64][n]
    unsigned short* __restrict__ ctx) {     // [b][n][768]
  __shared__ unsigned short Kl[2][64 * 64];  // [kv][d], swizzled
  __shared__ unsigned short Vl[2][64 * 64];  // [d][kv], swizzled
  const int bh = blockIdx.x;   // 96
  const int qt = blockIdx.y;   // 8
  const int tid = threadIdx.x;
  const int lane = tid & 63, wv = tid >> 6;
  const int q5 = lane & 31, hi = lane >> 5;

  const unsigned short* Qp =
      Q + ((size_t)bh * N_ + qt * 128 + wv * 32 + q5) * HD_;
  bf8_t qf[4];
#pragma unroll
  for (int s = 0; s < 4; ++s)
    qf[s] = *(const bf8_t*)&Qp[s * 16 + hi * 8];

  f16_t o0 = {}, o1 = {};
  float mrow = -1e30f, lrow = 0.f;
  const unsigned short* Kbase = Kb + (size_t)bh * N_ * HD_;
  const unsigned short* Vbase = Vt + (size_t)bh * HD_ * N_;

  auto stage = [&](int t, int buf) {        // 4 loads / thread
#pragma unroll
    for (int i = 0; i < 2; ++i) {
      int e = (i * 256 + tid) * 8;
      int r = e >> 6;
      int c = (e & 63) ^ swz(r);
      load_lds16(Kbase + (size_t)(t * 64 + r) * HD_ + c, &Kl[buf][e]);
      load_lds16(Vbase + (size_t)r * N_ + (t * 64 + c), &Vl[buf][e]);
    }
  };

  stage(0, 0);
  stage(1, 1);

  for (int t = 0; t < 16; ++t) {
    const int cur = t & 1;
    if (t + 1 < 16) { WAITV(4); } else { WAITV(0); }
    const unsigned short* Klc = Kl[cur];
    const unsigned short* Vlc = Vl[cur];

    f16_t s0 = {}, s1 = {};
    __builtin_amdgcn_s_setprio(1);
#pragma unroll
    for (int s = 0; s < 4; ++s) {
      int doff = s * 16 + hi * 8;
      bf8_t k0 = *(const bf8_t*)&Klc[(q5 * 64 + doff) ^ swz(q5)];
      bf8_t k1 = *(const bf8_t*)&Klc[((32 + q5) * 64 + doff) ^ swz(32 + q5)];
      s0 = __builtin_amdgcn_mfma_f32_32x32x16_bf16(k0, qf[s], s0, 0, 0, 0);
      s1 = __builtin_amdgcn_mfma_f32_32x32x16_bf16(k1, qf[s], s1, 0, 0, 0);
    }
    __builtin_amdgcn_s_setprio(0);

    float v0 = F3(s0[0], s0[1], s0[2]),   v1 = F3(s0[3], s0[4], s0[5]);
    float v2 = F3(s0[6], s0[7], s0[8]),   v3 = F3(s0[9], s0[10], s0[11]);
    float v4 = F3(s0[12], s0[13], s0[14]), v5 = F3(s0[15], s1[0], s1[1]);
    float v6 = F3(s1[2], s1[3], s1[4]),   v7 = F3(s1[5], s1[6], s1[7]);
    float v8 = F3(s1[8], s1[9], s1[10]),  v9 = F3(s1[11], s1[12], s1[13]);
    float w0 = F3(v0, v1, v2), w1 = F3(v3, v4, v5);
    float w2 = F3(v6, v7, v8), w3 = F3(v9, s1[14], s1[15]);
    float mx = fmaxf(F3(w0, w1, w2), w3);

    if (!__all(mx - mrow <= 8.0f)) {
      float Mx = fmaxf(mx, __shfl_xor(mx, 32, 64));
      float mnew = fmaxf(mrow, Mx);
      float al = exp2_hw(mrow - mnew);
      lrow *= al;
#pragma unroll
      for (int r = 0; r < 16; ++r) { o0[r] *= al; o1[r] *= al; }
      mrow = mnew;
    }

    float p[32];
#pragma unroll
    for (int r = 0; r < 16; ++r) p[r] = exp2_hw(s0[r] - mrow);
#pragma unroll
    for (int r = 0; r < 16; ++r) p[16 + r] = exp2_hw(s1[r] - mrow);
    float acc0 = 0.f, acc1 = 0.f, acc2 = 0.f, acc3 = 0.f;
#pragma unroll
    for (int r = 0; r < 8; ++r) {
      acc0 += p[r]; acc1 += p[8 + r]; acc2 += p[16 + r]; acc3 += p[24 + r];
    }
    lrow += (acc0 + acc1) + (acc2 + acc3);

    unsigned pj[4][4];
#pragma unroll
    for (int s = 0; s < 4; ++s) {
      unsigned Ax = cvt_pk_bf16(p[8 * s + 0], p[8 * s + 1]);
      unsigned Cx = cvt_pk_bf16(p[8 * s + 2], p[8 * s + 3]);
      unsigned Ex = cvt_pk_bf16(p[8 * s + 4], p[8 * s + 5]);
      unsigned Fx = cvt_pk_bf16(p[8 * s + 6], p[8 * s + 7]);
      asm volatile("v_permlane32_swap_b32 %0, %1" : "+v"(Ax), "+v"(Ex));
      asm volatile("v_permlane32_swap_b32 %0, %1" : "+v"(Cx), "+v"(Fx));
      pj[s][0] = Ax; pj[s][1] = Cx; pj[s][2] = Ex; pj[s][3] = Fx;
    }

    __builtin_amdgcn_s_setprio(1);
#pragma unroll
    for (int s = 0; s < 4; ++s) {
      int koff = s * 16 + hi * 8;
      bf8_t pb;
      *(uint4*)&pb = *(uint4*)&pj[s][0];
      bf8_t vv0 = *(const bf8_t*)&Vlc[(q5 * 64 + koff) ^ swz(q5)];
      bf8_t vv1 = *(const bf8_t*)&Vlc[((32 + q5) * 64 + koff) ^ swz(32 + q5)];
      o0 = __builtin_amdgcn_mfma_f32_32x32x16_bf16(vv0, pb, o0, 0, 0, 0);
      o1 = __builtin_amdgcn_mfma_f32_32x32x16_bf16(vv1, pb, o1, 0, 0, 0);
    }
    __builtin_amdgcn_s_setprio(0);

    BAR2();
    if (t + 2 < 16) stage(t + 2, cur);
  }

  lrow += __shfl_xor(lrow, 32, 64);
  float rinv = 1.0f / lrow;

  unsigned short* Ol = &Kl[0][0] + wv * 2048;   // per-wave 32q x 64d region
#pragma unroll
  for (int f = 0; f < 2; ++f) {
#pragma unroll
    for (int r = 0; r < 16; r += 2) {
      int d = (r & 3) + 8 * (r >> 2) + 4 * hi + 32 * f;
      float lo = (f ? o1[r] : o0[r]) * rinv;
      float hi2 = (f ? o1[r + 1] : o0[r + 1]) * rinv;
      unsigned pk = cvt_pk_bf16(lo, hi2);
      *(unsigned*)&Ol[q5 * 64 + (d ^ ((q5 & 7) << 3))] = pk;
    }
  }
  asm volatile("s_waitcnt lgkmcnt(0)" ::: "memory");
  __builtin_amdgcn_sched_barrier(0);

  const int bb = bh / H_, h = bh - bb * H_;
  const int qq = lane >> 1;
#pragma unroll
  for (int k = 0; k < 4; ++k) {
    int c = (lane & 1) * 4 + k;
    bf8_t val = *(const bf8_t*)&Ol[qq * 64 + ((c * 8) ^ ((qq & 7) << 3))];
    unsigned short* dst = ctx +
        ((size_t)bb * N_ + qt * 128 + wv * 32 + qq) * E_ + h * HD_ + c * 8;
    *(bf8_t*)dst = val;
  }
}

// ---------------- launch ----------------
extern "C" void kernel_launch(void* const* d_in, const int* in_sizes, int n_in,
                              void* d_out, int out_size, void* d_ws, size_t ws_size,
                              hipStream_t stream) {
  const float* x     = (const float*)d_in[0];
  const float* ln_g  = (const float*)d_in[1];
  const float* ln_b  = (const float*)d_in[2];
  const float* w_qkv = (const float*)d_in[3];
  const float* b_qkv = (const float*)d_in[4];
  const float* w_out = (const float*)d_in[5];
  const float* b_out = (const float*)d_in[6];
  float* out = (float*)d_out;

  char* ws = (char*)d_ws;
  const size_t SZ = (size_t)M_ * E_ * 2;
  unsigned short* xn    = (unsigned short*)(ws);
  unsigned short* qb    = (unsigned short*)(ws + SZ);
  unsigned short* kbuf  = (unsigned short*)(ws + 2 * SZ);
  unsigned short* vtb   = (unsigned short*)(ws + 3 * SZ);
  unsigned short* ctx   = (unsigned short*)(ws + 4 * SZ);
  unsigned short* wqkvb = (unsigned short*)(ws + 5 * SZ);
  unsigned short* woutb = (unsigned short*)(ws + 5 * SZ + (size_t)3 * E_ * E_ * 2);

  int n1 = 3 * E_ * E_ / 4;
  k_cast_bf16<<<(n1 + 255) / 256, 256, 0, stream>>>(w_qkv, wqkvb, n1);
  int n2 = E_ * E_ / 4;
  k_cast_bf16<<<(n2 + 255) / 256, 256, 0, stream>>>(w_out, woutb, n2);

  k_ln<<<M_, 192, 0, stream>>>(x, ln_g, ln_b, xn);

  k_gemm_bt<0><<<dim3(18, 64), 256, 0, stream>>>(xn, wqkvb, b_qkv, qb, kbuf, vtb,
                                                 nullptr, E_, 3 * E_);
  k_attn<<<dim3(96, 8), 256, 0, stream>>>(qb, kbuf, vtb, ctx);
  k_gemm_bt<1><<<dim3(6, 64), 256, 0, stream>>>(ctx, woutb, b_out, nullptr, nullptr,
                                                nullptr, out, E_, E_);
}

// Round 15
// 134.249 us; speedup vs baseline: 1.2998x; 1.2998x over previous
//
#include <hip/hip_runtime.h>
#include <hip/hip_bf16.h>
#include <stdint.h>

#define B_ 8
#define N_ 1024
#define E_ 768
#define H_ 12
#define HD_ 64
#define M_ (B_ * N_)   // 8192 rows

typedef __attribute__((ext_vector_type(8))) short bf8_t;    // 8 x bf16
typedef __attribute__((ext_vector_type(4))) float f4_t;     // 4 x f32
typedef __attribute__((ext_vector_type(16))) float f16_t;   // 16 x f32 (32x32 acc)

__device__ __forceinline__ unsigned short f2bf(float f) {
  unsigned u = __builtin_bit_cast(unsigned, f);
  unsigned r = (u + 0x7fffu + ((u >> 16) & 1u)) >> 16;  // RNE
  return (unsigned short)r;
}

__device__ __forceinline__ unsigned cvt_pk_bf16(float lo, float hi) {
  unsigned r;
  asm("v_cvt_pk_bf16_f32 %0, %1, %2" : "=v"(r) : "v"(lo), "v"(hi));
  return r;
}

__device__ __forceinline__ float exp2_hw(float x) {
  float r;
  asm("v_exp_f32 %0, %1" : "=v"(r) : "v"(x));
  return r;
}

__device__ __forceinline__ void load_lds16(const void* g, void* l) {
  __builtin_amdgcn_global_load_lds(
      (__attribute__((address_space(1))) void*)(g),
      (__attribute__((address_space(3))) void*)(l), 16, 0, 0);
}

#define WAITV(N)                                        \
  asm volatile("s_waitcnt vmcnt(" #N ")" ::: "memory"); \
  __builtin_amdgcn_sched_barrier(0);                    \
  __builtin_amdgcn_s_barrier();                         \
  __builtin_amdgcn_sched_barrier(0);

#define BAR2()                          \
  __builtin_amdgcn_sched_barrier(0);    \
  __builtin_amdgcn_s_barrier();         \
  __builtin_amdgcn_sched_barrier(0);

// XOR swizzle on the 8-elem (16B) chunk within a 64-elem (128B) row.
__device__ __forceinline__ int swz(int row) {
  return ((row ^ (row >> 3)) & 7) << 3;
}

#define F3(a, b, c) fmaxf(fmaxf((a), (b)), (c))   // fuses to v_max3_f32

// ---------------- weight fp32 -> bf16 cast (both weights, one launch) --------
__global__ void k_cast_bf16(const float* __restrict__ w1,
                            unsigned short* __restrict__ o1,
                            const float* __restrict__ w2,
                            unsigned short* __restrict__ o2,
                            int n1, int ntot) {
  int i = blockIdx.x * blockDim.x + threadIdx.x;
  if (i >= ntot) return;
  const float* src = (i < n1) ? w1 : w2;
  unsigned short* dst = (i < n1) ? o1 : o2;
  int j = (i < n1) ? i : i - n1;
  float4 v = ((const float4*)src)[j];
  ushort4 o;
  o.x = f2bf(v.x); o.y = f2bf(v.y); o.z = f2bf(v.z); o.w = f2bf(v.w);
  ((ushort4*)dst)[j] = o;
}

// ---------------- LayerNorm -> bf16 ----------------
__global__ __launch_bounds__(192) void k_ln(const float* __restrict__ x,
                                            const float* __restrict__ g,
                                            const float* __restrict__ bta,
                                            unsigned short* __restrict__ xn) {
  int row = blockIdx.x;  // 8192
  int t = threadIdx.x;   // 0..191
  float4 v = ((const float4*)(x + (size_t)row * E_))[t];
  float s = v.x + v.y + v.z + v.w;
  float s2 = v.x * v.x + v.y * v.y + v.z * v.z + v.w * v.w;
  for (int off = 32; off; off >>= 1) {
    s += __shfl_xor(s, off, 64);
    s2 += __shfl_xor(s2, off, 64);
  }
  __shared__ float red[6];
  int lane = t & 63, wv = t >> 6;
  if (lane == 0) { red[wv] = s; red[3 + wv] = s2; }
  __syncthreads();
  s = red[0] + red[1] + red[2];
  s2 = red[3] + red[4] + red[5];
  float mu = s * (1.0f / E_);
  float var = s2 * (1.0f / E_) - mu * mu;
  float rstd = rsqrtf(var + 1e-5f);
  float4 gg = ((const float4*)g)[t];
  float4 bb = ((const float4*)bta)[t];
  ushort4 o;
  o.x = f2bf((v.x - mu) * rstd * gg.x + bb.x);
  o.y = f2bf((v.y - mu) * rstd * gg.y + bb.y);
  o.z = f2bf((v.z - mu) * rstd * gg.z + bb.z);
  o.w = f2bf((v.w - mu) * rstd * gg.w + bb.w);
  ((ushort4*)(xn + (size_t)row * E_))[t] = o;
}

// ---------------- GEMM  C = A @ W^T + bias  (round-8 champion config) ---------
// BK=64 double-buffer, stage-ahead + __syncthreads, T1 XCD swizzle, T2 swizzle.
// EPI 0: scatter Q(*0.125*log2e)/K/V^T bf16;  EPI 1: dense fp32.
template <int EPI>
__global__ __launch_bounds__(256) void k_gemm_bt(
    const unsigned short* __restrict__ A,   // [M][K] bf16
    const unsigned short* __restrict__ W,   // [Nf][K] bf16
    const float* __restrict__ bias,         // [Nf]
    unsigned short* __restrict__ oQ, unsigned short* __restrict__ oK,
    unsigned short* __restrict__ oVt, float* __restrict__ oF,
    int K, int Nf) {
  __shared__ unsigned short Al[2][128 * 64];
  __shared__ unsigned short Bl[2][128 * 64];
  const int nbx = Nf >> 7;                  // 18 or 6
  const int nwg = nbx << 6;
  const int orig = blockIdx.y * nbx + blockIdx.x;
  const int id = (orig & 7) * (nwg >> 3) + (orig >> 3);
  const int n0 = (id % nbx) * 128, m0 = (id / nbx) * 128;
  const int tid = threadIdx.x;
  const int lane = tid & 63, wv = tid >> 6;
  const int wr = wv >> 1, wc = wv & 1;
  const int g = lane >> 4, l15 = lane & 15;
  f4_t acc[4][4] = {};

  auto stage = [&](int k0, int buf) {
#pragma unroll
    for (int i = 0; i < 4; ++i) {
      int e = (i * 256 + tid) * 8;
      int r = e >> 6;
      int c = (e & 63) ^ swz(r);
      load_lds16(A + (size_t)(m0 + r) * K + (k0 + c), &Al[buf][e]);
      load_lds16(W + (size_t)(n0 + r) * K + (k0 + c), &Bl[buf][e]);
    }
  };

  stage(0, 0);
  __syncthreads();
  int cur = 0;

  for (int k0 = 0; k0 < K; k0 += 64) {
    if (k0 + 64 < K) stage(k0 + 64, cur ^ 1);
    const unsigned short* Ac = Al[cur];
    const unsigned short* Bc = Bl[cur];
#pragma unroll
    for (int kk = 0; kk < 2; ++kk) {
      bf8_t af[4], bfr[4];
#pragma unroll
      for (int mi = 0; mi < 4; ++mi) {
        int ar = wr * 64 + mi * 16 + l15;
        af[mi] = *(const bf8_t*)&Ac[(ar * 64 + kk * 32 + g * 8) ^ swz(ar)];
      }
#pragma unroll
      for (int ni = 0; ni < 4; ++ni) {
        int br = wc * 64 + ni * 16 + l15;
        bfr[ni] = *(const bf8_t*)&Bc[(br * 64 + kk * 32 + g * 8) ^ swz(br)];
      }
#pragma unroll
      for (int mi = 0; mi < 4; ++mi)
#pragma unroll
        for (int ni = 0; ni < 4; ++ni)
          acc[mi][ni] = __builtin_amdgcn_mfma_f32_16x16x32_bf16(
              af[mi], bfr[ni], acc[mi][ni], 0, 0, 0);
    }
    __syncthreads();
    cur ^= 1;
  }

#pragma unroll
  for (int mi = 0; mi < 4; ++mi) {
#pragma unroll
    for (int ni = 0; ni < 4; ++ni) {
      int f = n0 + wc * 64 + ni * 16 + l15;
      float bs = bias[f];
#pragma unroll
      for (int i = 0; i < 4; ++i) {
        int m = m0 + wr * 64 + mi * 16 + g * 4 + i;
        float val = acc[mi][ni][i] + bs;
        if (EPI == 0) {
          int bb = m >> 10, n = m & 1023;
          int which = f / E_;
          int e2 = f - which * E_;
          int h = e2 >> 6, d = e2 & 63;
          size_t qk = (((size_t)bb * H_ + h) * N_ + n) * HD_ + d;
          if (which == 0) oQ[qk] = f2bf(val * 0.1803368801f);  // 0.125*log2(e)
          else if (which == 1) oK[qk] = f2bf(val);
          else oVt[(((size_t)bb * H_ + h) * HD_ + d) * N_ + n] = f2bf(val);
        } else {
          oF[(size_t)m * E_ + f] = val;
        }
      }
    }
  }
}

// ---------------- flash attention: 32x32 MFMA, in-register P ------------------
// 4 waves x 32 q-rows (128 q/block, grid 768 = 3 blocks/CU, full residency).
__global__ __launch_bounds__(256, 3) void k_attn(
    const unsigned short* __restrict__ Q,   // [bh][n][64], pre-scaled
    const unsigned short* __restrict__ Kb,  // [bh][n][64]
    const unsigned short* __restrict__ Vt,  // [bh][64][n]
    unsigned short* __restrict__ ctx) {     // [b][n][768]
  __shared__ unsigned short Kl[2][64 * 64];  // [kv][d], swizzled
  __shared__ unsigned short Vl[2][64 * 64];  // [d][kv], swizzled
  const int bh = blockIdx.x;   // 96
  const int qt = blockIdx.y;   // 8
  const int tid = threadIdx.x;
  const int lane = tid & 63, wv = tid >> 6;
  const int q5 = lane & 31, hi = lane >> 5;

  const unsigned short* Qp =
      Q + ((size_t)bh * N_ + qt * 128 + wv * 32 + q5) * HD_;
  bf8_t qf[4];
#pragma unroll
  for (int s = 0; s < 4; ++s)
    qf[s] = *(const bf8_t*)&Qp[s * 16 + hi * 8];

  f16_t o0 = {}, o1 = {};
  float mrow = -1e30f, lrow = 0.f;
  const unsigned short* Kbase = Kb + (size_t)bh * N_ * HD_;
  const unsigned short* Vbase = Vt + (size_t)bh * HD_ * N_;

  auto stage = [&](int t, int buf) {        // 4 loads / thread
#pragma unroll
    for (int i = 0; i < 2; ++i) {
      int e = (i * 256 + tid) * 8;
      int r = e >> 6;
      int c = (e & 63) ^ swz(r);
      load_lds16(Kbase + (size_t)(t * 64 + r) * HD_ + c, &Kl[buf][e]);
      load_lds16(Vbase + (size_t)r * N_ + (t * 64 + c), &Vl[buf][e]);
    }
  };

  stage(0, 0);
  stage(1, 1);

  for (int t = 0; t < 16; ++t) {
    const int cur = t & 1;
    if (t + 1 < 16) { WAITV(4); } else { WAITV(0); }
    const unsigned short* Klc = Kl[cur];
    const unsigned short* Vlc = Vl[cur];

    f16_t s0 = {}, s1 = {};
    __builtin_amdgcn_s_setprio(1);
#pragma unroll
    for (int s = 0; s < 4; ++s) {
      int doff = s * 16 + hi * 8;
      bf8_t k0 = *(const bf8_t*)&Klc[(q5 * 64 + doff) ^ swz(q5)];
      bf8_t k1 = *(const bf8_t*)&Klc[((32 + q5) * 64 + doff) ^ swz(32 + q5)];
      s0 = __builtin_amdgcn_mfma_f32_32x32x16_bf16(k0, qf[s], s0, 0, 0, 0);
      s1 = __builtin_amdgcn_mfma_f32_32x32x16_bf16(k1, qf[s], s1, 0, 0, 0);
    }
    __builtin_amdgcn_s_setprio(0);

    float v0 = F3(s0[0], s0[1], s0[2]),   v1 = F3(s0[3], s0[4], s0[5]);
    float v2 = F3(s0[6], s0[7], s0[8]),   v3 = F3(s0[9], s0[10], s0[11]);
    float v4 = F3(s0[12], s0[13], s0[14]), v5 = F3(s0[15], s1[0], s1[1]);
    float v6 = F3(s1[2], s1[3], s1[4]),   v7 = F3(s1[5], s1[6], s1[7]);
    float v8 = F3(s1[8], s1[9], s1[10]),  v9 = F3(s1[11], s1[12], s1[13]);
    float w0 = F3(v0, v1, v2), w1 = F3(v3, v4, v5);
    float w2 = F3(v6, v7, v8), w3 = F3(v9, s1[14], s1[15]);
    float mx = fmaxf(F3(w0, w1, w2), w3);

    if (!__all(mx - mrow <= 8.0f)) {
      float Mx = fmaxf(mx, __shfl_xor(mx, 32, 64));
      float mnew = fmaxf(mrow, Mx);
      float al = exp2_hw(mrow - mnew);
      lrow *= al;
#pragma unroll
      for (int r = 0; r < 16; ++r) { o0[r] *= al; o1[r] *= al; }
      mrow = mnew;
    }

    float p[32];
#pragma unroll
    for (int r = 0; r < 16; ++r) p[r] = exp2_hw(s0[r] - mrow);
#pragma unroll
    for (int r = 0; r < 16; ++r) p[16 + r] = exp2_hw(s1[r] - mrow);
    float acc0 = 0.f, acc1 = 0.f, acc2 = 0.f, acc3 = 0.f;
#pragma unroll
    for (int r = 0; r < 8; ++r) {
      acc0 += p[r]; acc1 += p[8 + r]; acc2 += p[16 + r]; acc3 += p[24 + r];
    }
    lrow += (acc0 + acc1) + (acc2 + acc3);

    unsigned pj[4][4];
#pragma unroll
    for (int s = 0; s < 4; ++s) {
      unsigned Ax = cvt_pk_bf16(p[8 * s + 0], p[8 * s + 1]);
      unsigned Cx = cvt_pk_bf16(p[8 * s + 2], p[8 * s + 3]);
      unsigned Ex = cvt_pk_bf16(p[8 * s + 4], p[8 * s + 5]);
      unsigned Fx = cvt_pk_bf16(p[8 * s + 6], p[8 * s + 7]);
      asm volatile("v_permlane32_swap_b32 %0, %1" : "+v"(Ax), "+v"(Ex));
      asm volatile("v_permlane32_swap_b32 %0, %1" : "+v"(Cx), "+v"(Fx));
      pj[s][0] = Ax; pj[s][1] = Cx; pj[s][2] = Ex; pj[s][3] = Fx;
    }

    __builtin_amdgcn_s_setprio(1);
#pragma unroll
    for (int s = 0; s < 4; ++s) {
      int koff = s * 16 + hi * 8;
      bf8_t pb;
      *(uint4*)&pb = *(uint4*)&pj[s][0];
      bf8_t vv0 = *(const bf8_t*)&Vlc[(q5 * 64 + koff) ^ swz(q5)];
      bf8_t vv1 = *(const bf8_t*)&Vlc[((32 + q5) * 64 + koff) ^ swz(32 + q5)];
      o0 = __builtin_amdgcn_mfma_f32_32x32x16_bf16(vv0, pb, o0, 0, 0, 0);
      o1 = __builtin_amdgcn_mfma_f32_32x32x16_bf16(vv1, pb, o1, 0, 0, 0);
    }
    __builtin_amdgcn_s_setprio(0);

    BAR2();
    if (t + 2 < 16) stage(t + 2, cur);
  }

  lrow += __shfl_xor(lrow, 32, 64);
  float rinv = 1.0f / lrow;

  unsigned short* Ol = &Kl[0][0] + wv * 2048;   // per-wave 32q x 64d region
#pragma unroll
  for (int f = 0; f < 2; ++f) {
#pragma unroll
    for (int r = 0; r < 16; r += 2) {
      int d = (r & 3) + 8 * (r >> 2) + 4 * hi + 32 * f;
      float lo = (f ? o1[r] : o0[r]) * rinv;
      float hi2 = (f ? o1[r + 1] : o0[r + 1]) * rinv;
      unsigned pk = cvt_pk_bf16(lo, hi2);
      *(unsigned*)&Ol[q5 * 64 + (d ^ ((q5 & 7) << 3))] = pk;
    }
  }
  asm volatile("s_waitcnt lgkmcnt(0)" ::: "memory");
  __builtin_amdgcn_sched_barrier(0);

  const int bb = bh / H_, h = bh - bb * H_;
  const int qq = lane >> 1;
#pragma unroll
  for (int k = 0; k < 4; ++k) {
    int c = (lane & 1) * 4 + k;
    bf8_t val = *(const bf8_t*)&Ol[qq * 64 + ((c * 8) ^ ((qq & 7) << 3))];
    unsigned short* dst = ctx +
        ((size_t)bb * N_ + qt * 128 + wv * 32 + qq) * E_ + h * HD_ + c * 8;
    *(bf8_t*)dst = val;
  }
}

// ---------------- launch ----------------
extern "C" void kernel_launch(void* const* d_in, const int* in_sizes, int n_in,
                              void* d_out, int out_size, void* d_ws, size_t ws_size,
                              hipStream_t stream) {
  const float* x     = (const float*)d_in[0];
  const float* ln_g  = (const float*)d_in[1];
  const float* ln_b  = (const float*)d_in[2];
  const float* w_qkv = (const float*)d_in[3];
  const float* b_qkv = (const float*)d_in[4];
  const float* w_out = (const float*)d_in[5];
  const float* b_out = (const float*)d_in[6];
  float* out = (float*)d_out;

  char* ws = (char*)d_ws;
  const size_t SZ = (size_t)M_ * E_ * 2;
  unsigned short* xn    = (unsigned short*)(ws);
  unsigned short* qb    = (unsigned short*)(ws + SZ);
  unsigned short* kbuf  = (unsigned short*)(ws + 2 * SZ);
  unsigned short* vtb   = (unsigned short*)(ws + 3 * SZ);
  unsigned short* ctx   = (unsigned short*)(ws + 4 * SZ);
  unsigned short* wqkvb = (unsigned short*)(ws + 5 * SZ);
  unsigned short* woutb = (unsigned short*)(ws + 5 * SZ + (size_t)3 * E_ * E_ * 2);

  int n1 = 3 * E_ * E_ / 4;      // float4 elements of w_qkv
  int n2 = E_ * E_ / 4;          // float4 elements of w_out
  int ntot = n1 + n2;
  k_cast_bf16<<<(ntot + 255) / 256, 256, 0, stream>>>(w_qkv, wqkvb, w_out,
                                                      woutb, n1, ntot);

  k_ln<<<M_, 192, 0, stream>>>(x, ln_g, ln_b, xn);

  k_gemm_bt<0><<<dim3(18, 64), 256, 0, stream>>>(xn, wqkvb, b_qkv, qb, kbuf, vtb,
                                                 nullptr, E_, 3 * E_);
  k_attn<<<dim3(96, 8), 256, 0, stream>>>(qb, kbuf, vtb, ctx);
  k_gemm_bt<1><<<dim3(6, 64), 256, 0, stream>>>(ctx, woutb, b_out, nullptr, nullptr,
                                                nullptr, out, E_, E_);
}